// Round 1
// baseline (1128.652 us; speedup 1.0000x reference)
//
#include <hip/hip_runtime.h>
#include <math.h>

#define D       128
#define NGRAPH  64
#define N0      1024
#define NE      (1<<20)
#define NTOT    (NGRAPH*N0)
#define MAXSLOT 128

// ---- static device workspace (avoids dependence on ws_size) ----
__device__ float g_h[NTOT*D];        // current node features (input of round)
__device__ float g_mean[NTOT*D];     // mean-aggregated neighbor features
__device__ float g_h2[NTOT*D];       // post-GEMM features
__device__ int   g_esrc[NE];
__device__ int   g_edst[NE];         // -1 marks invalid edge
__device__ int   g_adj[NTOT*MAXSLOT];
__device__ int   g_cnt[NTOT];
__device__ float g_score[NTOT];
__device__ int   g_selidx[NGRAPH*820];
__device__ float g_selval[NGRAPH*820];
__device__ int   g_newid[NTOT];
__device__ float g_pool[NGRAPH*8*256];
__device__ float g_s[NGRAPH*256];    // x1+x2+x3 accumulator

// ---------------- init: copy x and edges, zero s ----------------
__global__ void k_init(const float* __restrict__ x, const int* __restrict__ ei) {
    long stride = (long)gridDim.x * blockDim.x;
    long t0 = (long)blockIdx.x * blockDim.x + threadIdx.x;
    for (long i = t0; i < (long)NTOT * D; i += stride) g_h[i] = x[i];
    for (long e = t0; e < NE; e += stride) {
        g_esrc[e] = ei[e];
        g_edst[e] = ei[NE + e];
    }
    for (long i = t0; i < NGRAPH * 256; i += stride) g_s[i] = 0.f;
}

__global__ void k_zero_cnt(int n) {
    int stride = gridDim.x * blockDim.x;
    for (int i = blockIdx.x * blockDim.x + threadIdx.x; i < n; i += stride) g_cnt[i] = 0;
}

// ---------------- adjacency build (dst -> list of src) ----------------
__global__ void k_build_adj() {
    int stride = gridDim.x * blockDim.x;
    for (int e = blockIdx.x * blockDim.x + threadIdx.x; e < NE; e += stride) {
        int d = g_edst[e];
        if (d >= 0) {
            int s = g_esrc[e];
            int slot = atomicAdd(&g_cnt[d], 1);
            if (slot < MAXSLOT) g_adj[d * MAXSLOT + slot] = s;
        }
    }
}

// ---------------- mean aggregation: one wave per dst node ----------------
__global__ void k_aggregate(int n) {
    int gt = blockIdx.x * blockDim.x + threadIdx.x;
    int node = gt >> 6, lane = gt & 63;
    if (node >= n) return;
    int cnt = g_cnt[node];
    float ax = 0.f, ay = 0.f;
    const float2* hp = (const float2*)g_h;
    for (int i = 0; i < cnt; i++) {
        int s = g_adj[node * MAXSLOT + i];
        float2 v = hp[(size_t)s * 64 + lane];
        ax += v.x; ay += v.y;
    }
    float inv = 1.f / (float)(cnt > 0 ? cnt : 1);
    float2 o; o.x = ax * inv; o.y = ay * inv;
    ((float2*)g_mean)[(size_t)node * 64 + lane] = o;
}

// ------- fused SAGE GEMM: h2 = relu(mean@Wl + h@Wr + bl) -------
// 256 rows/block; each lane owns one full output row (acc[128] in regs).
__global__ __launch_bounds__(256) void k_fused_gemm(const float* __restrict__ Wl,
                                                    const float* __restrict__ Wr,
                                                    const float* __restrict__ bl,
                                                    int nrows) {
    __shared__ float lds_w[32 * 128];
    __shared__ float lds_x[256 * 33];
    int tid = threadIdx.x;
    int row0 = blockIdx.x * 256;
    float acc[128];
#pragma unroll
    for (int c = 0; c < 128; c++) acc[c] = 0.f;

    for (int half = 0; half < 2; half++) {
        const float* __restrict__ X = half ? g_h : g_mean;
        const float* __restrict__ W = half ? Wr : Wl;
        for (int kc = 0; kc < 128; kc += 32) {
            __syncthreads();
#pragma unroll 4
            for (int i = 0; i < 16; i++) {          // stage W[kc..kc+32][0..127]
                int idx = tid + i * 256;
                lds_w[idx] = W[(kc + (idx >> 7)) * 128 + (idx & 127)];
            }
#pragma unroll 4
            for (int i = 0; i < 32; i++) {          // stage X rows, padded stride 33
                int idx = tid + i * 256;
                int r = idx >> 5, k = idx & 31;
                lds_x[r * 33 + k] = X[(size_t)(row0 + r) * 128 + kc + k];
            }
            __syncthreads();
            for (int kk = 0; kk < 32; kk++) {
                float xv = lds_x[tid * 33 + kk];
                const float4* wr4 = (const float4*)(lds_w + kk * 128);
#pragma unroll
                for (int c4 = 0; c4 < 32; c4++) {
                    float4 wv = wr4[c4];
                    acc[c4 * 4 + 0] += xv * wv.x;
                    acc[c4 * 4 + 1] += xv * wv.y;
                    acc[c4 * 4 + 2] += xv * wv.z;
                    acc[c4 * 4 + 3] += xv * wv.w;
                }
            }
        }
    }
    size_t orow = (size_t)(row0 + tid) * 128;
#pragma unroll
    for (int c4 = 0; c4 < 32; c4++) {
        float4 o;
        o.x = fmaxf(acc[c4 * 4 + 0] + bl[c4 * 4 + 0], 0.f);
        o.y = fmaxf(acc[c4 * 4 + 1] + bl[c4 * 4 + 1], 0.f);
        o.z = fmaxf(acc[c4 * 4 + 2] + bl[c4 * 4 + 2], 0.f);
        o.w = fmaxf(acc[c4 * 4 + 3] + bl[c4 * 4 + 3], 0.f);
        ((float4*)(g_h2 + orow))[c4] = o;
    }
}

// ---------------- scores: tanh(h2 . pw / ||pw||), one wave per node ----------------
__global__ void k_score(const float* __restrict__ pw, int n) {
    int gt = blockIdx.x * blockDim.x + threadIdx.x;
    int node = gt >> 6, lane = gt & 63;
    if (node >= n) return;
    float2 w = ((const float2*)pw)[lane];
    float2 h = ((const float2*)g_h2)[(size_t)node * 64 + lane];
    float dot = h.x * w.x + h.y * w.y;
    float nn = w.x * w.x + w.y * w.y;
    for (int off = 32; off; off >>= 1) {
        dot += __shfl_xor(dot, off);
        nn  += __shfl_xor(nn, off);
    }
    if (lane == 0) g_score[node] = tanhf(dot / sqrtf(nn));
}

// ---------------- per-graph top-K via bitonic sort (desc) ----------------
__global__ void k_topk(int M, int K) {
    __shared__ float sc[1024];
    __shared__ int   id[1024];
    int g = blockIdx.x, tid = threadIdx.x;
    for (int i = tid; i < 1024; i += 512) {
        sc[i] = (i < M) ? g_score[g * M + i] : -INFINITY;
        id[i] = i;
    }
    for (int i = tid; i < M; i += 512) g_newid[g * M + i] = -1;
    __syncthreads();
    for (int k = 2; k <= 1024; k <<= 1) {
        for (int j = k >> 1; j > 0; j >>= 1) {
            for (int i = tid; i < 1024; i += 512) {
                int ixj = i ^ j;
                if (ixj > i) {
                    bool desc = ((i & k) == 0);
                    float a = sc[i], b = sc[ixj];
                    bool sw = desc ? (a < b) : (a > b);
                    if (sw) {
                        sc[i] = b; sc[ixj] = a;
                        int t = id[i]; id[i] = id[ixj]; id[ixj] = t;
                    }
                }
            }
            __syncthreads();
        }
    }
    for (int j = tid; j < K; j += 512) {
        int li = id[j];
        g_selidx[g * K + j] = g * M + li;
        g_selval[g * K + j] = sc[j];
        g_newid[g * M + li] = g * K + j;
    }
}

// ------- gather x_new = h2[sel]*val into g_h, partial max/sum readout -------
__global__ void k_gather_pool(int K) {
    int g = blockIdx.x, chunk = blockIdx.y;
    int cs = (K + 7) / 8;
    int j0 = chunk * cs, j1 = min(K, j0 + cs);
    int tid = threadIdx.x;
    int c = tid & 127, half = tid >> 7;
    float mx = -INFINITY, sm = 0.f;
    for (int j = j0 + half; j < j1; j += 2) {
        int srcRow = g_selidx[g * K + j];
        float v = g_h2[(size_t)srcRow * 128 + c] * g_selval[g * K + j];
        g_h[((size_t)(g * K + j)) * 128 + c] = v;
        mx = fmaxf(mx, v); sm += v;
    }
    __shared__ float smx[256], ssm[256];
    smx[tid] = mx; ssm[tid] = sm;
    __syncthreads();
    if (half == 0) {
        mx = fmaxf(mx, smx[tid + 128]);
        sm += ssm[tid + 128];
        g_pool[(g * 8 + chunk) * 256 + c] = mx;
        g_pool[(g * 8 + chunk) * 256 + 128 + c] = sm;
    }
}

__global__ void k_pool_combine(int K) {
    int g = blockIdx.x, tid = threadIdx.x;
    if (tid < 128) {
        float mx = -INFINITY;
        for (int ch = 0; ch < 8; ch++) mx = fmaxf(mx, g_pool[(g * 8 + ch) * 256 + tid]);
        g_s[g * 256 + tid] += mx;
    } else {
        int c = tid - 128;
        float sm = 0.f;
        for (int ch = 0; ch < 8; ch++) sm += g_pool[(g * 8 + ch) * 256 + 128 + c];
        g_s[g * 256 + 128 + c] += sm / (float)K;
    }
}

// ---------------- edge remap ----------------
__global__ void k_remap() {
    int stride = gridDim.x * blockDim.x;
    for (int e = blockIdx.x * blockDim.x + threadIdx.x; e < NE; e += stride) {
        int d = g_edst[e];
        if (d < 0) continue;
        int ns = g_newid[g_esrc[e]];
        int nd = g_newid[d];
        if (ns < 0 || nd < 0) g_edst[e] = -1;
        else { g_esrc[e] = ns; g_edst[e] = nd; }
    }
}

// ---------------- final MLP head ----------------
__global__ void k_mlp(const float* __restrict__ W1, const float* __restrict__ b1,
                      const float* __restrict__ W2, const float* __restrict__ b2,
                      const float* __restrict__ W3, const float* __restrict__ b3,
                      float* __restrict__ out) {
    int g = blockIdx.x, tid = threadIdx.x;   // 128 threads
    __shared__ float h1[128], h2[64], red[128];
    float a = 0.f;
    for (int k = 0; k < 256; k++) a += g_s[g * 256 + k] * W1[k * 128 + tid];
    h1[tid] = fmaxf(a + b1[tid], 0.f);
    __syncthreads();
    if (tid < 64) {
        float a2 = 0.f;
        for (int k = 0; k < 128; k++) a2 += h1[k] * W2[k * 64 + tid];
        h2[tid] = fmaxf(a2 + b2[tid], 0.f);
    }
    __syncthreads();
    red[tid] = (tid < 64) ? h2[tid] * W3[tid] : 0.f;
    __syncthreads();
    for (int s = 64; s > 0; s >>= 1) {
        if (tid < s) red[tid] += red[tid + s];
        __syncthreads();
    }
    if (tid == 0) {
        float z = red[0] + b3[0];
        out[g] = 1.f / (1.f + expf(-z));
    }
}

extern "C" void kernel_launch(void* const* d_in, const int* in_sizes, int n_in,
                              void* d_out, int out_size, void* d_ws, size_t ws_size,
                              hipStream_t stream) {
    const float* x  = (const float*)d_in[0];
    const int*   ei = (const int*)d_in[1];
    const float* Wl[3] = {(const float*)d_in[2], (const float*)d_in[6],  (const float*)d_in[10]};
    const float* bl[3] = {(const float*)d_in[3], (const float*)d_in[7],  (const float*)d_in[11]};
    const float* Wr[3] = {(const float*)d_in[4], (const float*)d_in[8],  (const float*)d_in[12]};
    const float* pw[3] = {(const float*)d_in[5], (const float*)d_in[9],  (const float*)d_in[13]};
    const float* W1 = (const float*)d_in[14]; const float* b1 = (const float*)d_in[15];
    const float* W2 = (const float*)d_in[16]; const float* b2 = (const float*)d_in[17];
    const float* W3 = (const float*)d_in[18]; const float* b3 = (const float*)d_in[19];
    float* out = (float*)d_out;

    const int Ms[3] = {1024, 820, 656};
    const int Ks[3] = {820, 656, 525};

    k_init<<<2048, 256, 0, stream>>>(x, ei);

    for (int r = 0; r < 3; r++) {
        int M = Ms[r], K = Ks[r];
        int n = NGRAPH * M;
        k_zero_cnt<<<256, 256, 0, stream>>>(n);
        k_build_adj<<<2048, 256, 0, stream>>>();
        k_aggregate<<<(n + 3) / 4, 256, 0, stream>>>(n);
        k_fused_gemm<<<n / 256, 256, 0, stream>>>(Wl[r], Wr[r], bl[r], n);
        k_score<<<(n + 3) / 4, 256, 0, stream>>>(pw[r], n);
        k_topk<<<NGRAPH, 512, 0, stream>>>(M, K);
        k_gather_pool<<<dim3(NGRAPH, 8), 256, 0, stream>>>(K);
        k_pool_combine<<<NGRAPH, 256, 0, stream>>>(K);
        if (r < 2) k_remap<<<2048, 256, 0, stream>>>();
    }
    k_mlp<<<NGRAPH, 128, 0, stream>>>(W1, b1, W2, b2, W3, b3, out);
}

// Round 3
// 689.671 us; speedup vs baseline: 1.6365x; 1.6365x over previous
//
#include <hip/hip_runtime.h>
#include <math.h>

#define D       128
#define NGRAPH  64
#define N0      1024
#define NE      (1<<20)
#define NTOT    (NGRAPH*N0)
#define MAXSLOT 128

// ---- static device workspace (referenced ONLY from device code) ----
__device__ float g_h[NTOT*D];        // gathered features (input of rounds 1,2)
__device__ float g_mean[NTOT*D];     // mean-aggregated neighbor features
__device__ float g_h2[NTOT*D];       // post-GEMM features
__device__ int   g_esrc[NE];
__device__ int   g_edst[NE];         // -1 marks invalid edge
__device__ int   g_adj[NTOT*MAXSLOT];
__device__ int   g_cnt[NTOT];
__device__ float g_score[NTOT];
__device__ int   g_selidx[NGRAPH*820];
__device__ float g_selval[NGRAPH*820];
__device__ int   g_newid[NTOT];
__device__ float g_pool[NGRAPH*8*256];
__device__ float g_s[NGRAPH*256];

typedef __attribute__((ext_vector_type(8))) short bf16x8;
typedef __attribute__((ext_vector_type(4))) float f32x4;

__device__ inline unsigned short f2bf_rne(float f) {
    unsigned u = __float_as_uint(f);
    u += 0x7FFF + ((u >> 16) & 1);
    return (unsigned short)(u >> 16);
}

// ---------------- tiny init: zero s accumulator ----------------
__global__ void k_init_s() {
    int i = blockIdx.x * 256 + threadIdx.x;
    if (i < NGRAPH * 256) g_s[i] = 0.f;
}

__global__ void k_zero_cnt(int n) {
    int stride = gridDim.x * blockDim.x;
    for (int i = blockIdx.x * blockDim.x + threadIdx.x; i < n; i += stride) g_cnt[i] = 0;
}

// ---------------- adjacency build (dst -> list of src) ----------------
__global__ void k_build_adj(const int* __restrict__ ei, int use_input) {
    const int* es = use_input ? ei : g_esrc;
    const int* ed = use_input ? (ei + NE) : g_edst;
    int stride = gridDim.x * blockDim.x;
    for (int e = blockIdx.x * blockDim.x + threadIdx.x; e < NE; e += stride) {
        int d = ed[e];
        if (d >= 0) {
            int s = es[e];
            int slot = atomicAdd(&g_cnt[d], 1);
            if (slot < MAXSLOT) g_adj[d * MAXSLOT + slot] = s;
        }
    }
}

// ------- mean aggregation: wave = 2 nodes (32 lanes each, float4/lane) -------
__global__ __launch_bounds__(256) void k_aggregate(const float* __restrict__ x_in,
                                                   int use_input, int n) {
    const float* X = use_input ? x_in : g_h;
    int wid = threadIdx.x >> 6, lane = threadIdx.x & 63;
    int half = lane >> 5, li = lane & 31;
    int node = blockIdx.x * 8 + wid * 2 + half;   // n % 8 == 0 always here
    int cnt = (node < n) ? min(g_cnt[node], MAXSLOT) : 0;
    int cnt2 = max(cnt, __shfl_xor(cnt, 32));
    float ax = 0.f, ay = 0.f, az = 0.f, aw = 0.f;
    const float4* Xp = (const float4*)X;
    for (int base = 0; base < cnt2; base += 32) {
        int a = (base + li < cnt) ? g_adj[node * MAXSLOT + base + li] : 0;
        int mm = min(cnt2 - base, 32);
        for (int i = 0; i < mm; i++) {
            int s = __shfl(a, half * 32 + i);
            if (base + i < cnt) {
                float4 v = Xp[(size_t)s * 32 + li];
                ax += v.x; ay += v.y; az += v.z; aw += v.w;
            }
        }
    }
    if (node < n) {
        float inv = 1.f / (float)max(cnt, 1);
        float4 o; o.x = ax * inv; o.y = ay * inv; o.z = az * inv; o.w = aw * inv;
        ((float4*)g_mean)[(size_t)node * 32 + li] = o;
    }
}

// ------- fused SAGE GEMM via split-bf16 MFMA -------
// h2 = relu([mean|h] @ [Wl;Wr] + bl), K=256. Block: 128 rows x 128 cols,
// 4 waves (2x2), each wave 64x64 = 4x4 tiles of 16x16x32 MFMA.
// f32 = hi(bf16) + lo(bf16); acc = Ahi*Bhi + Ahi*Blo + Alo*Bhi.
__global__ __launch_bounds__(256, 2) void k_gemm(const float* __restrict__ x_in,
                                                 int use_input,
                                                 const float* __restrict__ Wl,
                                                 const float* __restrict__ Wr,
                                                 const float* __restrict__ bl) {
    // stride 40 ushorts (80 B): bank step 20 dwords, gcd(20,32)=4 -> 2-way (free)
    __shared__ __align__(16) unsigned short sa_hi[128 * 40];
    __shared__ __align__(16) unsigned short sa_lo[128 * 40];
    __shared__ __align__(16) unsigned short sb_hi[128 * 40];
    __shared__ __align__(16) unsigned short sb_lo[128 * 40];
    const float* Xr = use_input ? x_in : g_h;
    int tid = threadIdx.x;
    int row0 = blockIdx.x * 128;
    int wid = tid >> 6, lane = tid & 63;
    int wr = wid >> 1, wc = wid & 1;
    int lrow = lane & 15, kgrp = lane >> 4;

    f32x4 acc[4][4];
#pragma unroll
    for (int mi = 0; mi < 4; mi++)
#pragma unroll
        for (int ni = 0; ni < 4; ni++)
#pragma unroll
            for (int r = 0; r < 4; r++) acc[mi][ni][r] = 0.f;

    for (int kc = 0; kc < 256; kc += 32) {
        const float* __restrict__ Xsrc = (kc < 128) ? g_mean : Xr;
        const float* __restrict__ Wsrc = (kc < 128) ? Wl : Wr;
        int kloc = kc & 127;
        __syncthreads();
        // stage A: 128 rows x 32 k  (1024 float4s)
#pragma unroll
        for (int i = 0; i < 4; i++) {
            int f = tid + i * 256;
            int row = f >> 3, kq = f & 7;
            float4 v = ((const float4*)(Xsrc + (size_t)(row0 + row) * 128 + kloc))[kq];
            ushort4 h4, l4;
            h4.x = f2bf_rne(v.x); l4.x = f2bf_rne(v.x - __uint_as_float((unsigned)h4.x << 16));
            h4.y = f2bf_rne(v.y); l4.y = f2bf_rne(v.y - __uint_as_float((unsigned)h4.y << 16));
            h4.z = f2bf_rne(v.z); l4.z = f2bf_rne(v.z - __uint_as_float((unsigned)h4.z << 16));
            h4.w = f2bf_rne(v.w); l4.w = f2bf_rne(v.w - __uint_as_float((unsigned)h4.w << 16));
            *(ushort4*)&sa_hi[row * 40 + kq * 4] = h4;
            *(ushort4*)&sa_lo[row * 40 + kq * 4] = l4;
        }
        // stage B transposed: [col][k]  (1024 float4s)
#pragma unroll
        for (int i = 0; i < 4; i++) {
            int f = tid + i * 256;
            int k = f >> 5, cq = f & 31;
            float4 v = ((const float4*)(Wsrc + (size_t)(kloc + k) * 128))[cq];
            float vv[4] = {v.x, v.y, v.z, v.w};
#pragma unroll
            for (int j = 0; j < 4; j++) {
                unsigned short h = f2bf_rne(vv[j]);
                unsigned short l = f2bf_rne(vv[j] - __uint_as_float((unsigned)h << 16));
                sb_hi[(cq * 4 + j) * 40 + k] = h;
                sb_lo[(cq * 4 + j) * 40 + k] = l;
            }
        }
        __syncthreads();
        // fragments: A row = lane&15, k = (lane>>4)*8 + j ; B col = lane&15, same k
        bf16x8 ah[4], al[4], bh[4], blo[4];
#pragma unroll
        for (int mi = 0; mi < 4; mi++) {
            int r = wr * 64 + mi * 16 + lrow;
            ah[mi] = *(const bf16x8*)&sa_hi[r * 40 + kgrp * 8];
            al[mi] = *(const bf16x8*)&sa_lo[r * 40 + kgrp * 8];
        }
#pragma unroll
        for (int ni = 0; ni < 4; ni++) {
            int c = wc * 64 + ni * 16 + lrow;
            bh[ni] = *(const bf16x8*)&sb_hi[c * 40 + kgrp * 8];
            blo[ni] = *(const bf16x8*)&sb_lo[c * 40 + kgrp * 8];
        }
#pragma unroll
        for (int mi = 0; mi < 4; mi++)
#pragma unroll
            for (int ni = 0; ni < 4; ni++) {
                acc[mi][ni] = __builtin_amdgcn_mfma_f32_16x16x32_bf16(ah[mi], bh[ni], acc[mi][ni], 0, 0, 0);
                acc[mi][ni] = __builtin_amdgcn_mfma_f32_16x16x32_bf16(ah[mi], blo[ni], acc[mi][ni], 0, 0, 0);
                acc[mi][ni] = __builtin_amdgcn_mfma_f32_16x16x32_bf16(al[mi], bh[ni], acc[mi][ni], 0, 0, 0);
            }
    }
    // epilogue: C/D col = lane&15, row = (lane>>4)*4 + reg  [m89-verified layout]
#pragma unroll
    for (int mi = 0; mi < 4; mi++)
#pragma unroll
        for (int ni = 0; ni < 4; ni++) {
            int c = wc * 64 + ni * 16 + lrow;
            float b = bl[c];
#pragma unroll
            for (int r = 0; r < 4; r++) {
                int row = row0 + wr * 64 + mi * 16 + kgrp * 4 + r;
                g_h2[(size_t)row * 128 + c] = fmaxf(acc[mi][ni][r] + b, 0.f);
            }
        }
}

// ---------------- scores: tanh(h2 . pw / ||pw||), one wave per node ----------------
__global__ void k_score(const float* __restrict__ pw, int n) {
    int gt = blockIdx.x * blockDim.x + threadIdx.x;
    int node = gt >> 6, lane = gt & 63;
    if (node >= n) return;
    float2 w = ((const float2*)pw)[lane];
    float2 h = ((const float2*)g_h2)[(size_t)node * 64 + lane];
    float dot = h.x * w.x + h.y * w.y;
    float nn = w.x * w.x + w.y * w.y;
    for (int off = 32; off; off >>= 1) {
        dot += __shfl_xor(dot, off);
        nn  += __shfl_xor(nn, off);
    }
    if (lane == 0) g_score[node] = tanhf(dot / sqrtf(nn));
}

// ---------------- per-graph top-K via bitonic sort (desc) ----------------
__global__ void k_topk(int M, int K) {
    __shared__ float sc[1024];
    __shared__ int   id[1024];
    int g = blockIdx.x, tid = threadIdx.x;
    for (int i = tid; i < 1024; i += 512) {
        sc[i] = (i < M) ? g_score[g * M + i] : -INFINITY;
        id[i] = i;
    }
    for (int i = tid; i < M; i += 512) g_newid[g * M + i] = -1;
    __syncthreads();
    for (int k = 2; k <= 1024; k <<= 1) {
        for (int j = k >> 1; j > 0; j >>= 1) {
            for (int i = tid; i < 1024; i += 512) {
                int ixj = i ^ j;
                if (ixj > i) {
                    bool desc = ((i & k) == 0);
                    float a = sc[i], b = sc[ixj];
                    bool sw = desc ? (a < b) : (a > b);
                    if (sw) {
                        sc[i] = b; sc[ixj] = a;
                        int t = id[i]; id[i] = id[ixj]; id[ixj] = t;
                    }
                }
            }
            __syncthreads();
        }
    }
    for (int j = tid; j < K; j += 512) {
        int li = id[j];
        g_selidx[g * K + j] = g * M + li;
        g_selval[g * K + j] = sc[j];
        g_newid[g * M + li] = g * K + j;
    }
}

// ------- gather x_new = h2[sel]*val into g_h, partial max/sum readout -------
__global__ void k_gather_pool(int K) {
    int g = blockIdx.x, chunk = blockIdx.y;
    int cs = (K + 7) / 8;
    int j0 = chunk * cs, j1 = min(K, j0 + cs);
    int tid = threadIdx.x;
    int c = tid & 127, half = tid >> 7;
    float mx = -INFINITY, sm = 0.f;
    for (int j = j0 + half; j < j1; j += 2) {
        int srcRow = g_selidx[g * K + j];
        float v = g_h2[(size_t)srcRow * 128 + c] * g_selval[g * K + j];
        g_h[((size_t)(g * K + j)) * 128 + c] = v;
        mx = fmaxf(mx, v); sm += v;
    }
    __shared__ float smx[256], ssm[256];
    smx[tid] = mx; ssm[tid] = sm;
    __syncthreads();
    if (half == 0) {
        mx = fmaxf(mx, smx[tid + 128]);
        sm += ssm[tid + 128];
        g_pool[(g * 8 + chunk) * 256 + c] = mx;
        g_pool[(g * 8 + chunk) * 256 + 128 + c] = sm;
    }
}

__global__ void k_pool_combine(int K) {
    int g = blockIdx.x, tid = threadIdx.x;
    if (tid < 128) {
        float mx = -INFINITY;
        for (int ch = 0; ch < 8; ch++) mx = fmaxf(mx, g_pool[(g * 8 + ch) * 256 + tid]);
        g_s[g * 256 + tid] += mx;
    } else {
        int c = tid - 128;
        float sm = 0.f;
        for (int ch = 0; ch < 8; ch++) sm += g_pool[(g * 8 + ch) * 256 + 128 + c];
        g_s[g * 256 + 128 + c] += sm / (float)K;
    }
}

// ---------------- edge remap ----------------
__global__ void k_remap(const int* __restrict__ ei, int use_input) {
    const int* es = use_input ? ei : g_esrc;
    const int* ed = use_input ? (ei + NE) : g_edst;
    int stride = gridDim.x * blockDim.x;
    for (int e = blockIdx.x * blockDim.x + threadIdx.x; e < NE; e += stride) {
        int d = ed[e];
        if (d < 0) { g_edst[e] = -1; continue; }
        int ns = g_newid[es[e]];
        int nd = g_newid[d];
        if (ns < 0 || nd < 0) g_edst[e] = -1;
        else { g_esrc[e] = ns; g_edst[e] = nd; }
    }
}

// ---------------- final MLP head ----------------
__global__ void k_mlp(const float* __restrict__ W1, const float* __restrict__ b1,
                      const float* __restrict__ W2, const float* __restrict__ b2,
                      const float* __restrict__ W3, const float* __restrict__ b3,
                      float* __restrict__ out) {
    int g = blockIdx.x, tid = threadIdx.x;   // 128 threads
    __shared__ float h1[128], h2[64], red[128];
    float a = 0.f;
    for (int k = 0; k < 256; k++) a += g_s[g * 256 + k] * W1[k * 128 + tid];
    h1[tid] = fmaxf(a + b1[tid], 0.f);
    __syncthreads();
    if (tid < 64) {
        float a2 = 0.f;
        for (int k = 0; k < 128; k++) a2 += h1[k] * W2[k * 64 + tid];
        h2[tid] = fmaxf(a2 + b2[tid], 0.f);
    }
    __syncthreads();
    red[tid] = (tid < 64) ? h2[tid] * W3[tid] : 0.f;
    __syncthreads();
    for (int s = 64; s > 0; s >>= 1) {
        if (tid < s) red[tid] += red[tid + s];
        __syncthreads();
    }
    if (tid == 0) {
        float z = red[0] + b3[0];
        out[g] = 1.f / (1.f + expf(-z));
    }
}

extern "C" void kernel_launch(void* const* d_in, const int* in_sizes, int n_in,
                              void* d_out, int out_size, void* d_ws, size_t ws_size,
                              hipStream_t stream) {
    const float* x  = (const float*)d_in[0];
    const int*   ei = (const int*)d_in[1];
    const float* Wl[3] = {(const float*)d_in[2], (const float*)d_in[6],  (const float*)d_in[10]};
    const float* bl[3] = {(const float*)d_in[3], (const float*)d_in[7],  (const float*)d_in[11]};
    const float* Wr[3] = {(const float*)d_in[4], (const float*)d_in[8],  (const float*)d_in[12]};
    const float* pw[3] = {(const float*)d_in[5], (const float*)d_in[9],  (const float*)d_in[13]};
    const float* W1 = (const float*)d_in[14]; const float* b1 = (const float*)d_in[15];
    const float* W2 = (const float*)d_in[16]; const float* b2 = (const float*)d_in[17];
    const float* W3 = (const float*)d_in[18]; const float* b3 = (const float*)d_in[19];
    float* out = (float*)d_out;

    const int Ms[3] = {1024, 820, 656};
    const int Ks[3] = {820, 656, 525};

    k_init_s<<<64, 256, 0, stream>>>();

    for (int r = 0; r < 3; r++) {
        int M = Ms[r], K = Ks[r];
        int n = NGRAPH * M;                      // 65536 / 52480 / 41984 (all %128==0)
        int use_input = (r == 0) ? 1 : 0;
        k_zero_cnt<<<256, 256, 0, stream>>>(n);
        k_build_adj<<<2048, 256, 0, stream>>>(ei, use_input);
        k_aggregate<<<n / 8, 256, 0, stream>>>(x, use_input, n);
        k_gemm<<<n / 128, 256, 0, stream>>>(x, use_input, Wl[r], Wr[r], bl[r]);
        k_score<<<n / 4, 256, 0, stream>>>(pw[r], n);
        k_topk<<<NGRAPH, 512, 0, stream>>>(M, K);
        k_gather_pool<<<dim3(NGRAPH, 8), 256, 0, stream>>>(K);
        k_pool_combine<<<NGRAPH, 256, 0, stream>>>(K);
        if (r < 2) k_remap<<<2048, 256, 0, stream>>>(ei, use_input);
    }
    k_mlp<<<NGRAPH, 128, 0, stream>>>(W1, b1, W2, b2, W3, b3, out);
}

// Round 4
// 613.730 us; speedup vs baseline: 1.8390x; 1.1237x over previous
//
#include <hip/hip_runtime.h>
#include <math.h>

#define D       128
#define NGRAPH  64
#define N0      1024
#define NE      (1<<20)
#define EPG     (NE/NGRAPH)      // 16384 edges per graph (fixed slots)
#define NTOT    (NGRAPH*N0)
#define MAXSLOT 128

// ---- static device workspace (referenced ONLY from device code) ----
__device__ float g_h[NTOT*D];            // gathered features f32 (gather path)
__device__ float g_h2[NTOT*D];           // post-GEMM features
__device__ unsigned short g_mh[NTOT*D];  // mean  hi-plane (GEMM A, k<128)
__device__ unsigned short g_ml[NTOT*D];  // mean  lo-plane
__device__ unsigned short g_xh[NTOT*D];  // right hi-plane (GEMM A, k>=128)
__device__ unsigned short g_xl[NTOT*D];  // right lo-plane
__device__ unsigned short g_wbh[3*128*256]; // W stacked+transposed hi [r][c][k]
__device__ unsigned short g_wbl[3*128*256];
__device__ int   g_esrc[NE];
__device__ int   g_edst[NE];             // -1 marks invalid edge
__device__ int   g_adj[NTOT*MAXSLOT];
__device__ int   g_cnt[NTOT];
__device__ float g_dot[NTOT];            // h2 . pw  (pre-tanh, pre-norm)
__device__ float g_pwnorm[3];
__device__ int   g_selidx[NGRAPH*820];
__device__ float g_selval[NGRAPH*820];
__device__ int   g_newid[NTOT];
__device__ float g_pool[NGRAPH*8*256];
__device__ float g_s[NGRAPH*256];

typedef __attribute__((ext_vector_type(8))) short bf16x8;
typedef __attribute__((ext_vector_type(8))) unsigned short ushort8;
typedef __attribute__((ext_vector_type(4))) float f32x4;

__device__ inline unsigned short f2bf_rne(float f) {
    unsigned u = __float_as_uint(f);
    u += 0x7FFF + ((u >> 16) & 1);
    return (unsigned short)(u >> 16);
}
__device__ inline void split2(float v, unsigned short& h, unsigned short& l) {
    h = f2bf_rne(v);
    l = f2bf_rne(v - __uint_as_float((unsigned)h << 16));
}

// ---------------- init: zero s accumulator ----------------
__global__ void k_init_s() {
    int i = blockIdx.x * 256 + threadIdx.x;
    if (i < NGRAPH * 256) g_s[i] = 0.f;
}

// ---- prep: W stacked [Wl;Wr], transposed to [c][k], split hi/lo ----
__global__ void k_prep_w(const float* __restrict__ Wl1, const float* __restrict__ Wr1,
                         const float* __restrict__ Wl2, const float* __restrict__ Wr2,
                         const float* __restrict__ Wl3, const float* __restrict__ Wr3) {
    int t = blockIdx.x * 256 + threadIdx.x;      // < 3*128*256
    int r = t >> 15, rem = t & 32767;
    int c = rem >> 8, k = rem & 255;
    const float* WlR = (r == 0) ? Wl1 : (r == 1) ? Wl2 : Wl3;
    const float* WrR = (r == 0) ? Wr1 : (r == 1) ? Wr2 : Wr3;
    float v = (k < 128) ? WlR[k * 128 + c] : WrR[(k - 128) * 128 + c];
    split2(v, g_wbh[t], g_wbl[t]);
}

__global__ void k_norms(const float* __restrict__ p1, const float* __restrict__ p2,
                        const float* __restrict__ p3) {
    int r = blockIdx.x, lane = threadIdx.x;
    const float* p = (r == 0) ? p1 : (r == 1) ? p2 : p3;
    float a = p[lane], b = p[lane + 64];
    float s = a * a + b * b;
    for (int off = 32; off; off >>= 1) s += __shfl_xor(s, off);
    if (lane == 0) g_pwnorm[r] = sqrtf(s);
}

// ---- prep: round-0 x -> right-operand hi/lo planes ----
__global__ void k_prep_x(const float* __restrict__ x) {
    int t = blockIdx.x * 256 + threadIdx.x;      // < NTOT*D/4
    float4 v = ((const float4*)x)[t];
    ushort4 h4, l4;
    split2(v.x, h4.x, l4.x); split2(v.y, h4.y, l4.y);
    split2(v.z, h4.z, l4.z); split2(v.w, h4.w, l4.w);
    ((ushort4*)g_xh)[t] = h4;
    ((ushort4*)g_xl)[t] = l4;
}

__global__ void k_zero_cnt(int n) {
    int stride = gridDim.x * blockDim.x;
    for (int i = blockIdx.x * blockDim.x + threadIdx.x; i < n; i += stride) {
        g_cnt[i] = 0; g_dot[i] = 0.f;
    }
}

// ---- adjacency build, graph-local blocks (graph g -> XCD g%8) ----
__global__ void k_build_adj(const int* __restrict__ ei, int use_input) {
    const int* es = use_input ? ei : g_esrc;
    const int* ed = use_input ? (ei + NE) : g_edst;
    int b = blockIdx.x;
    int j = b >> 3;
    int g = (b & 7) + 8 * (j >> 6);              // EPB = EPG/256 = 64
    int ib = j & 63;
    int e = g * EPG + ib * 256 + threadIdx.x;
    int d = ed[e];
    if (d >= 0) {
        int s = es[e];
        int slot = atomicAdd(&g_cnt[d], 1);
        if (slot < MAXSLOT) g_adj[d * MAXSLOT + slot] = s;
    }
}

// ---- mean aggregation: wave = 2 nodes (32 lanes/node, float4/lane) ----
// graph-local XCD mapping; 4-way ILP gather; emits mean hi/lo planes.
__global__ __launch_bounds__(256) void k_aggregate(const float* __restrict__ x_in,
                                                   int use_input, int M, int BPG) {
    const float* X = use_input ? x_in : g_h;
    int b = blockIdx.x;
    int j = b >> 3;
    int g = (b & 7) + 8 * (j / BPG);
    int ib = j % BPG;
    int wid = threadIdx.x >> 6, lane = threadIdx.x & 63;
    int half = lane >> 5, li = lane & 31;
    int local = ib * 8 + wid * 2 + half;
    int node = g * M + local;
    int cnt = (local < M) ? min(g_cnt[node], MAXSLOT) : 0;
    int cnt2 = max(cnt, __shfl_xor(cnt, 32));
    float ax = 0.f, ay = 0.f, az = 0.f, aw = 0.f;
    const float4* Xp = (const float4*)X;
    int abase = node * MAXSLOT;
    for (int base = 0; base < cnt2; base += 32) {
        int a = (base + li < cnt) ? g_adj[abase + base + li] : -1;
        int mm = min(cnt2 - base, 32);
        int mmr = (mm + 3) & ~3;
        for (int i = 0; i < mmr; i += 4) {
            int s0 = __shfl(a, half * 32 + i + 0);
            int s1 = __shfl(a, half * 32 + i + 1);
            int s2 = __shfl(a, half * 32 + i + 2);
            int s3 = __shfl(a, half * 32 + i + 3);
            float4 v0 = Xp[(size_t)max(s0, 0) * 32 + li];
            float4 v1 = Xp[(size_t)max(s1, 0) * 32 + li];
            float4 v2 = Xp[(size_t)max(s2, 0) * 32 + li];
            float4 v3 = Xp[(size_t)max(s3, 0) * 32 + li];
            float m0 = (s0 >= 0) ? 1.f : 0.f, m1 = (s1 >= 0) ? 1.f : 0.f;
            float m2 = (s2 >= 0) ? 1.f : 0.f, m3 = (s3 >= 0) ? 1.f : 0.f;
            ax += m0 * v0.x + m1 * v1.x + m2 * v2.x + m3 * v3.x;
            ay += m0 * v0.y + m1 * v1.y + m2 * v2.y + m3 * v3.y;
            az += m0 * v0.z + m1 * v1.z + m2 * v2.z + m3 * v3.z;
            aw += m0 * v0.w + m1 * v1.w + m2 * v2.w + m3 * v3.w;
        }
    }
    if (local < M) {
        float inv = 1.f / (float)max(cnt, 1);
        ushort4 h4, l4;
        split2(ax * inv, h4.x, l4.x); split2(ay * inv, h4.y, l4.y);
        split2(az * inv, h4.z, l4.z); split2(aw * inv, h4.w, l4.w);
        *(ushort4*)&g_mh[(size_t)node * 128 + li * 4] = h4;
        *(ushort4*)&g_ml[(size_t)node * 128 + li * 4] = l4;
    }
}

// ---- fused SAGE GEMM (split-bf16 MFMA) + fused score dot ----
// h2 = relu([mean|xr] @ [Wl;Wr] + bl); g_dot[row] = h2[row] . pw
__global__ __launch_bounds__(256, 2) void k_gemm(int r,
                                                 const float* __restrict__ bl,
                                                 const float* __restrict__ pw) {
    __shared__ __align__(16) unsigned short sa_hi[128 * 40];
    __shared__ __align__(16) unsigned short sa_lo[128 * 40];
    __shared__ __align__(16) unsigned short sb_hi[128 * 40];
    __shared__ __align__(16) unsigned short sb_lo[128 * 40];
    const unsigned short* Wbh = g_wbh + r * 32768;
    const unsigned short* Wbl = g_wbl + r * 32768;
    int tid = threadIdx.x;
    int row0 = blockIdx.x * 128;
    int wid = tid >> 6, lane = tid & 63;
    int wr = wid >> 1, wc = wid & 1;
    int lrow = lane & 15, kgrp = lane >> 4;

    f32x4 acc[4][4];
#pragma unroll
    for (int mi = 0; mi < 4; mi++)
#pragma unroll
        for (int ni = 0; ni < 4; ni++)
#pragma unroll
            for (int q = 0; q < 4; q++) acc[mi][ni][q] = 0.f;

    for (int kc = 0; kc < 256; kc += 32) {
        const unsigned short* Ah = (kc < 128) ? g_mh : g_xh;
        const unsigned short* Al = (kc < 128) ? g_ml : g_xl;
        int kloc = kc & 127;
        __syncthreads();
#pragma unroll
        for (int i = 0; i < 2; i++) {            // A: 128 rows x 32 k, 2 planes
            int f = tid + i * 256;
            int row = f >> 2, kq = f & 3;
            size_t src = (size_t)(row0 + row) * 128 + kloc + kq * 8;
            *(ushort8*)&sa_hi[row * 40 + kq * 8] = *(const ushort8*)&Ah[src];
            *(ushort8*)&sa_lo[row * 40 + kq * 8] = *(const ushort8*)&Al[src];
        }
#pragma unroll
        for (int i = 0; i < 2; i++) {            // B: 128 cols x 32 k, 2 planes
            int f = tid + i * 256;
            int c = f >> 2, kq = f & 3;
            size_t src = (size_t)c * 256 + kc + kq * 8;
            *(ushort8*)&sb_hi[c * 40 + kq * 8] = *(const ushort8*)&Wbh[src];
            *(ushort8*)&sb_lo[c * 40 + kq * 8] = *(const ushort8*)&Wbl[src];
        }
        __syncthreads();
        bf16x8 ah[4], al[4], bh[4], blo[4];
#pragma unroll
        for (int mi = 0; mi < 4; mi++) {
            int rr = wr * 64 + mi * 16 + lrow;
            ah[mi] = *(const bf16x8*)&sa_hi[rr * 40 + kgrp * 8];
            al[mi] = *(const bf16x8*)&sa_lo[rr * 40 + kgrp * 8];
        }
#pragma unroll
        for (int ni = 0; ni < 4; ni++) {
            int c = wc * 64 + ni * 16 + lrow;
            bh[ni]  = *(const bf16x8*)&sb_hi[c * 40 + kgrp * 8];
            blo[ni] = *(const bf16x8*)&sb_lo[c * 40 + kgrp * 8];
        }
#pragma unroll
        for (int mi = 0; mi < 4; mi++)
#pragma unroll
            for (int ni = 0; ni < 4; ni++) {
                acc[mi][ni] = __builtin_amdgcn_mfma_f32_16x16x32_bf16(ah[mi], bh[ni],  acc[mi][ni], 0, 0, 0);
                acc[mi][ni] = __builtin_amdgcn_mfma_f32_16x16x32_bf16(ah[mi], blo[ni], acc[mi][ni], 0, 0, 0);
                acc[mi][ni] = __builtin_amdgcn_mfma_f32_16x16x32_bf16(al[mi], bh[ni],  acc[mi][ni], 0, 0, 0);
            }
    }
    // epilogue: C/D col = lane&15, row = (lane>>4)*4 + reg; fused pw-dot
    float pwv[4];
#pragma unroll
    for (int ni = 0; ni < 4; ni++) pwv[ni] = pw[wc * 64 + ni * 16 + lrow];
#pragma unroll
    for (int mi = 0; mi < 4; mi++) {
        float dotq[4] = {0.f, 0.f, 0.f, 0.f};
#pragma unroll
        for (int ni = 0; ni < 4; ni++) {
            int c = wc * 64 + ni * 16 + lrow;
            float b = bl[c];
#pragma unroll
            for (int q = 0; q < 4; q++) {
                float v = fmaxf(acc[mi][ni][q] + b, 0.f);
                g_h2[(size_t)(row0 + wr * 64 + mi * 16 + kgrp * 4 + q) * 128 + c] = v;
                dotq[q] += v * pwv[ni];
            }
        }
#pragma unroll
        for (int q = 0; q < 4; q++) {
            float dv = dotq[q];
            dv += __shfl_xor(dv, 1); dv += __shfl_xor(dv, 2);
            dv += __shfl_xor(dv, 4); dv += __shfl_xor(dv, 8);
            if (lrow == 0)
                atomicAdd(&g_dot[row0 + wr * 64 + mi * 16 + kgrp * 4 + q], dv);
        }
    }
}

// ---- per-graph top-K on raw dots (tanh monotonic); selval = tanh(dot/||pw||) ----
__global__ void k_topk(int M, int K, int rr) {
    __shared__ float sc[1024];
    __shared__ int   id[1024];
    int g = blockIdx.x, tid = threadIdx.x;
    float invn = 1.f / g_pwnorm[rr];
    for (int i = tid; i < 1024; i += 512) {
        sc[i] = (i < M) ? g_dot[g * M + i] : -INFINITY;
        id[i] = i;
    }
    for (int i = tid; i < M; i += 512) g_newid[g * M + i] = -1;
    __syncthreads();
    for (int k = 2; k <= 1024; k <<= 1) {
        for (int j = k >> 1; j > 0; j >>= 1) {
            for (int i = tid; i < 1024; i += 512) {
                int ixj = i ^ j;
                if (ixj > i) {
                    bool desc = ((i & k) == 0);
                    float a = sc[i], b = sc[ixj];
                    bool sw = desc ? (a < b) : (a > b);
                    if (sw) {
                        sc[i] = b; sc[ixj] = a;
                        int t = id[i]; id[i] = id[ixj]; id[ixj] = t;
                    }
                }
            }
            __syncthreads();
        }
    }
    for (int j = tid; j < K; j += 512) {
        int li = id[j];
        g_selidx[g * K + j] = g * M + li;
        g_selval[g * K + j] = tanhf(sc[j] * invn);
        g_newid[g * M + li] = g * K + j;
    }
}

// ---- gather x_new = h2[sel]*val -> g_h (f32) + hi/lo planes; partial readout ----
__global__ void k_gather_pool(int K) {
    int g = blockIdx.x, chunk = blockIdx.y;   // gridDim=(64,8): linear b%8 = g%8
    int cs = (K + 7) / 8;
    int j0 = chunk * cs, j1 = min(K, j0 + cs);
    int tid = threadIdx.x;
    int c = tid & 127, half = tid >> 7;
    float mx = -INFINITY, sm = 0.f;
    for (int j = j0 + half; j < j1; j += 2) {
        int srcRow = g_selidx[g * K + j];
        float v = g_h2[(size_t)srcRow * 128 + c] * g_selval[g * K + j];
        size_t o = (size_t)(g * K + j) * 128 + c;
        g_h[o] = v;
        split2(v, g_xh[o], g_xl[o]);
        mx = fmaxf(mx, v); sm += v;
    }
    __shared__ float smx[256], ssm[256];
    smx[tid] = mx; ssm[tid] = sm;
    __syncthreads();
    if (half == 0) {
        mx = fmaxf(mx, smx[tid + 128]);
        sm += ssm[tid + 128];
        g_pool[(g * 8 + chunk) * 256 + c] = mx;
        g_pool[(g * 8 + chunk) * 256 + 128 + c] = sm;
    }
}

__global__ void k_pool_combine(int K) {
    int g = blockIdx.x, tid = threadIdx.x;
    if (tid < 128) {
        float mx = -INFINITY;
        for (int ch = 0; ch < 8; ch++) mx = fmaxf(mx, g_pool[(g * 8 + ch) * 256 + tid]);
        g_s[g * 256 + tid] += mx;
    } else {
        int c = tid - 128;
        float sm = 0.f;
        for (int ch = 0; ch < 8; ch++) sm += g_pool[(g * 8 + ch) * 256 + 128 + c];
        g_s[g * 256 + 128 + c] += sm / (float)K;
    }
}

// ---- edge remap, graph-local blocks ----
__global__ void k_remap(const int* __restrict__ ei, int use_input) {
    const int* es = use_input ? ei : g_esrc;
    const int* ed = use_input ? (ei + NE) : g_edst;
    int b = blockIdx.x;
    int j = b >> 3;
    int g = (b & 7) + 8 * (j >> 6);
    int ib = j & 63;
    int e = g * EPG + ib * 256 + threadIdx.x;
    int d = ed[e];
    if (d < 0) { g_edst[e] = -1; return; }
    int ns = g_newid[es[e]];
    int nd = g_newid[d];
    if (ns < 0 || nd < 0) g_edst[e] = -1;
    else { g_esrc[e] = ns; g_edst[e] = nd; }
}

// ---- final MLP head ----
__global__ void k_mlp(const float* __restrict__ W1, const float* __restrict__ b1,
                      const float* __restrict__ W2, const float* __restrict__ b2,
                      const float* __restrict__ W3, const float* __restrict__ b3,
                      float* __restrict__ out) {
    int g = blockIdx.x, tid = threadIdx.x;   // 128 threads
    __shared__ float h1[128], h2[64], red[128];
    float a = 0.f;
    for (int k = 0; k < 256; k++) a += g_s[g * 256 + k] * W1[k * 128 + tid];
    h1[tid] = fmaxf(a + b1[tid], 0.f);
    __syncthreads();
    if (tid < 64) {
        float a2 = 0.f;
        for (int k = 0; k < 128; k++) a2 += h1[k] * W2[k * 64 + tid];
        h2[tid] = fmaxf(a2 + b2[tid], 0.f);
    }
    __syncthreads();
    red[tid] = (tid < 64) ? h2[tid] * W3[tid] : 0.f;
    __syncthreads();
    for (int s = 64; s > 0; s >>= 1) {
        if (tid < s) red[tid] += red[tid + s];
        __syncthreads();
    }
    if (tid == 0) {
        float z = red[0] + b3[0];
        out[g] = 1.f / (1.f + expf(-z));
    }
}

extern "C" void kernel_launch(void* const* d_in, const int* in_sizes, int n_in,
                              void* d_out, int out_size, void* d_ws, size_t ws_size,
                              hipStream_t stream) {
    const float* x  = (const float*)d_in[0];
    const int*   ei = (const int*)d_in[1];
    const float* Wl[3] = {(const float*)d_in[2], (const float*)d_in[6],  (const float*)d_in[10]};
    const float* bl[3] = {(const float*)d_in[3], (const float*)d_in[7],  (const float*)d_in[11]};
    const float* Wr[3] = {(const float*)d_in[4], (const float*)d_in[8],  (const float*)d_in[12]};
    const float* pw[3] = {(const float*)d_in[5], (const float*)d_in[9],  (const float*)d_in[13]};
    const float* W1 = (const float*)d_in[14]; const float* b1 = (const float*)d_in[15];
    const float* W2 = (const float*)d_in[16]; const float* b2 = (const float*)d_in[17];
    const float* W3 = (const float*)d_in[18]; const float* b3 = (const float*)d_in[19];
    float* out = (float*)d_out;

    const int Ms[3] = {1024, 820, 656};
    const int Ks[3] = {820, 656, 525};

    k_init_s<<<64, 256, 0, stream>>>();
    k_prep_w<<<384, 256, 0, stream>>>(Wl[0], Wr[0], Wl[1], Wr[1], Wl[2], Wr[2]);
    k_norms<<<3, 64, 0, stream>>>(pw[0], pw[1], pw[2]);
    k_prep_x<<<NTOT * D / 4 / 256, 256, 0, stream>>>(x);

    for (int r = 0; r < 3; r++) {
        int M = Ms[r], K = Ks[r];
        int n = NGRAPH * M;                      // 65536 / 52480 / 41984 (all %128==0)
        int BPG = (M + 7) / 8;
        int use_input = (r == 0) ? 1 : 0;
        k_zero_cnt<<<256, 256, 0, stream>>>(n);
        k_build_adj<<<NGRAPH * (EPG / 256), 256, 0, stream>>>(ei, use_input);
        k_aggregate<<<NGRAPH * BPG, 256, 0, stream>>>(x, use_input, M, BPG);
        k_gemm<<<n / 128, 256, 0, stream>>>(r, bl[r], pw[r]);
        k_topk<<<NGRAPH, 512, 0, stream>>>(M, K, r);
        k_gather_pool<<<dim3(NGRAPH, 8), 256, 0, stream>>>(K);
        k_pool_combine<<<NGRAPH, 256, 0, stream>>>(K);
        if (r < 2) k_remap<<<NGRAPH * (EPG / 256), 256, 0, stream>>>(ei, use_input);
    }
    k_mlp<<<NGRAPH, 128, 0, stream>>>(W1, b1, W2, b2, W3, b3, out);
}

// Round 10
// 508.094 us; speedup vs baseline: 2.2213x; 1.2079x over previous
//
#include <hip/hip_runtime.h>
#include <math.h>

#define D       128
#define NGRAPH  64
#define N0      1024
#define NE      (1<<20)
#define EPG     (NE/NGRAPH)      // 16384 edges per graph (contiguous slots)
#define NTOT    (NGRAPH*N0)
#define ASLOT   64               // max in-degree ~45 (Poisson 16); P(>64) ~ 1e-18

// ---- static device workspace (referenced ONLY from device code) ----
__device__ float g_h[NTOT*D];            // gathered features f32 (gather path)
__device__ float g_h2[NTOT*D];           // post-GEMM features
__device__ unsigned short g_mh[NTOT*D];  // mean  hi-plane (GEMM A, k<128)
__device__ unsigned short g_ml[NTOT*D];  // mean  lo-plane
__device__ unsigned short g_xh[NTOT*D];  // right hi-plane (GEMM A, k>=128)
__device__ unsigned short g_xl[NTOT*D];  // right lo-plane
__device__ unsigned short g_wbh[3*128*256]; // W stacked+transposed hi [r][c][k]
__device__ unsigned short g_wbl[3*128*256];
__device__ int   g_adjA[NTOT*ASLOT];     // ping-pong adjacency (rounds 0,2)
__device__ int   g_adjB[NTOT*ASLOT];     // round 1
__device__ int   g_cntA[NTOT];
__device__ int   g_cntB[NTOT];
__device__ float g_dot[NTOT];            // h2 . pw  (pre-tanh, pre-norm)
__device__ float g_pwnorm[3];
__device__ int   g_selidx[NGRAPH*820];
__device__ float g_selval[NGRAPH*820];
__device__ int   g_newid[NTOT];
__device__ float g_pool[3*NGRAPH*8*256]; // per-round partial readouts
typedef __attribute__((ext_vector_type(8))) short bf16x8;
typedef __attribute__((ext_vector_type(8))) unsigned short ushort8;
typedef __attribute__((ext_vector_type(4))) float f32x4;

__device__ inline unsigned short f2bf_rne(float f) {
    unsigned u = __float_as_uint(f);
    u += 0x7FFF + ((u >> 16) & 1);
    return (unsigned short)(u >> 16);
}
__device__ inline void split2(float v, unsigned short& h, unsigned short& l) {
    h = f2bf_rne(v);
    l = f2bf_rne(v - __uint_as_float((unsigned)h << 16));
}

// ---- prep: W stacked [Wl;Wr], transposed to [c][k], split hi/lo ----
__global__ void k_prep_w(const float* __restrict__ Wl1, const float* __restrict__ Wr1,
                         const float* __restrict__ Wl2, const float* __restrict__ Wr2,
                         const float* __restrict__ Wl3, const float* __restrict__ Wr3) {
    int t = blockIdx.x * 256 + threadIdx.x;      // < 3*128*256
    int r = t >> 15, rem = t & 32767;
    int c = rem >> 8, k = rem & 255;
    const float* WlR = (r == 0) ? Wl1 : (r == 1) ? Wl2 : Wl3;
    const float* WrR = (r == 0) ? Wr1 : (r == 1) ? Wr2 : Wr3;
    float v = (k < 128) ? WlR[k * 128 + c] : WrR[(k - 128) * 128 + c];
    split2(v, g_wbh[t], g_wbl[t]);
}

__global__ void k_norms(const float* __restrict__ p1, const float* __restrict__ p2,
                        const float* __restrict__ p3) {
    int r = blockIdx.x, lane = threadIdx.x;
    const float* p = (r == 0) ? p1 : (r == 1) ? p2 : p3;
    float a = p[lane], b = p[lane + 64];
    float s = a * a + b * b;
    for (int off = 32; off; off >>= 1) s += __shfl_xor(s, off);
    if (lane == 0) g_pwnorm[r] = sqrtf(s);
}

// ---- prep: round-0 x -> right-operand hi/lo planes ----
__global__ void k_prep_x(const float* __restrict__ x) {
    int t = blockIdx.x * 256 + threadIdx.x;      // < NTOT*D/4
    float4 v = ((const float4*)x)[t];
    ushort4 h4, l4;
    split2(v.x, h4.x, l4.x); split2(v.y, h4.y, l4.y);
    split2(v.z, h4.z, l4.z); split2(v.w, h4.w, l4.w);
    ((ushort4*)g_xh)[t] = h4;
    ((ushort4*)g_xl)[t] = l4;
}

// ---- round-0 adjacency: one block per graph, LDS slot counters ----
__global__ __launch_bounds__(1024) void k_badj0(const int* __restrict__ ei) {
    __shared__ int s_fill[N0];
    int g = blockIdx.x, tid = threadIdx.x;
    s_fill[tid] = 0;
    __syncthreads();
    int e0 = g * EPG;
#pragma unroll
    for (int i = 0; i < EPG / 1024; i++) {
        int e = e0 + i * 1024 + tid;
        int s = ei[e];
        int d = ei[NE + e];
        int slot = atomicAdd(&s_fill[d - g * N0], 1);
        if (slot < ASLOT) g_adjA[(size_t)d * ASLOT + slot] = s;
    }
    __syncthreads();
    g_cntA[g * N0 + tid] = min(s_fill[tid], ASLOT);
}

// ---- rounds 1-2: ballot-compact surviving adjacency (no atomics) ----
// dir=0: A->B (round1) ; dir=1: B->A (round2)
__global__ __launch_bounds__(256) void k_compact(int n_new, int dir) {
    int wid = threadIdx.x >> 6, lane = threadIdx.x & 63;
    int nj = blockIdx.x * 4 + wid;
    if (nj >= n_new) return;
    int old = g_selidx[nj];
    const int* adjO = dir ? g_adjB : g_adjA;
    const int* cntO = dir ? g_cntB : g_cntA;
    int* adjN = dir ? g_adjA : g_adjB;
    int* cntN = dir ? g_cntA : g_cntB;
    int cnt = cntO[old];
    int m = -1;
    if (lane < cnt) m = g_newid[adjO[(size_t)old * ASLOT + lane]];
    unsigned long long mask = __ballot(m >= 0);
    int pos = __popcll(mask & ((1ull << lane) - 1ull));
    if (m >= 0) adjN[(size_t)nj * ASLOT + pos] = m;
    if (lane == 0) cntN[nj] = __popcll(mask);
}

// ---- mean aggregation: wave = 2 nodes (32 lanes/node, float4/lane) ----
// graph-local XCD mapping; 4-way ILP gather; emits mean hi/lo planes + zeroes g_dot.
__global__ __launch_bounds__(256) void k_aggregate(const float* __restrict__ x_in,
                                                   int use_input, int ab, int M, int BPG) {
    const float* X = use_input ? x_in : g_h;
    const int* adj = ab ? g_adjB : g_adjA;
    const int* cntp = ab ? g_cntB : g_cntA;
    int b = blockIdx.x;
    int j = b >> 3;
    int g = (b & 7) + 8 * (j / BPG);
    int ib = j % BPG;
    int wid = threadIdx.x >> 6, lane = threadIdx.x & 63;
    int half = lane >> 5, li = lane & 31;
    int local = ib * 8 + wid * 2 + half;
    int node = g * M + local;
    int cnt = (local < M) ? cntp[node] : 0;
    int cnt2 = max(cnt, __shfl_xor(cnt, 32));
    float ax = 0.f, ay = 0.f, az = 0.f, aw = 0.f;
    const float4* Xp = (const float4*)X;
    size_t abase = (size_t)node * ASLOT;
    for (int base = 0; base < cnt2; base += 32) {
        int a = (base + li < cnt) ? adj[abase + base + li] : -1;
        int mm = min(cnt2 - base, 32);
        int mmr = (mm + 3) & ~3;
        for (int i = 0; i < mmr; i += 4) {
            int s0 = __shfl(a, half * 32 + i + 0);
            int s1 = __shfl(a, half * 32 + i + 1);
            int s2 = __shfl(a, half * 32 + i + 2);
            int s3 = __shfl(a, half * 32 + i + 3);
            float4 v0 = Xp[(size_t)max(s0, 0) * 32 + li];
            float4 v1 = Xp[(size_t)max(s1, 0) * 32 + li];
            float4 v2 = Xp[(size_t)max(s2, 0) * 32 + li];
            float4 v3 = Xp[(size_t)max(s3, 0) * 32 + li];
            float m0 = (s0 >= 0) ? 1.f : 0.f, m1 = (s1 >= 0) ? 1.f : 0.f;
            float m2 = (s2 >= 0) ? 1.f : 0.f, m3 = (s3 >= 0) ? 1.f : 0.f;
            ax += m0 * v0.x + m1 * v1.x + m2 * v2.x + m3 * v3.x;
            ay += m0 * v0.y + m1 * v1.y + m2 * v2.y + m3 * v3.y;
            az += m0 * v0.z + m1 * v1.z + m2 * v2.z + m3 * v3.z;
            aw += m0 * v0.w + m1 * v1.w + m2 * v2.w + m3 * v3.w;
        }
    }
    if (local < M) {
        float inv = 1.f / (float)max(cnt, 1);
        ushort4 h4, l4;
        split2(ax * inv, h4.x, l4.x); split2(ay * inv, h4.y, l4.y);
        split2(az * inv, h4.z, l4.z); split2(aw * inv, h4.w, l4.w);
        *(ushort4*)&g_mh[(size_t)node * 128 + li * 4] = h4;
        *(ushort4*)&g_ml[(size_t)node * 128 + li * 4] = l4;
        if (li == 0) g_dot[node] = 0.f;   // BUGFIX r5: was lane==0 (skipped half=1 nodes)
    }
}

// ---- fused SAGE GEMM (split-bf16 MFMA) + fused score dot ----
// h2 = relu([mean|xr] @ [Wl;Wr] + bl); g_dot[row] = h2[row] . pw
__global__ __launch_bounds__(256, 2) void k_gemm(int r,
                                                 const float* __restrict__ bl,
                                                 const float* __restrict__ pw) {
    __shared__ __align__(16) unsigned short sa_hi[128 * 40];
    __shared__ __align__(16) unsigned short sa_lo[128 * 40];
    __shared__ __align__(16) unsigned short sb_hi[128 * 40];
    __shared__ __align__(16) unsigned short sb_lo[128 * 40];
    const unsigned short* Wbh = g_wbh + r * 32768;
    const unsigned short* Wbl = g_wbl + r * 32768;
    int tid = threadIdx.x;
    int row0 = blockIdx.x * 128;
    int wid = tid >> 6, lane = tid & 63;
    int wr = wid >> 1, wc = wid & 1;
    int lrow = lane & 15, kgrp = lane >> 4;

    f32x4 acc[4][4];
#pragma unroll
    for (int mi = 0; mi < 4; mi++)
#pragma unroll
        for (int ni = 0; ni < 4; ni++)
#pragma unroll
            for (int q = 0; q < 4; q++) acc[mi][ni][q] = 0.f;

    for (int kc = 0; kc < 256; kc += 32) {
        const unsigned short* Ah = (kc < 128) ? g_mh : g_xh;
        const unsigned short* Al = (kc < 128) ? g_ml : g_xl;
        int kloc = kc & 127;
        __syncthreads();
#pragma unroll
        for (int i = 0; i < 2; i++) {            // A: 128 rows x 32 k, 2 planes
            int f = tid + i * 256;
            int row = f >> 2, kq = f & 3;
            size_t src = (size_t)(row0 + row) * 128 + kloc + kq * 8;
            *(ushort8*)&sa_hi[row * 40 + kq * 8] = *(const ushort8*)&Ah[src];
            *(ushort8*)&sa_lo[row * 40 + kq * 8] = *(const ushort8*)&Al[src];
        }
#pragma unroll
        for (int i = 0; i < 2; i++) {            // B: 128 cols x 32 k, 2 planes
            int f = tid + i * 256;
            int c = f >> 2, kq = f & 3;
            size_t src = (size_t)c * 256 + kc + kq * 8;
            *(ushort8*)&sb_hi[c * 40 + kq * 8] = *(const ushort8*)&Wbh[src];
            *(ushort8*)&sb_lo[c * 40 + kq * 8] = *(const ushort8*)&Wbl[src];
        }
        __syncthreads();
        bf16x8 ah[4], al[4], bh[4], blo[4];
#pragma unroll
        for (int mi = 0; mi < 4; mi++) {
            int rr = wr * 64 + mi * 16 + lrow;
            ah[mi] = *(const bf16x8*)&sa_hi[rr * 40 + kgrp * 8];
            al[mi] = *(const bf16x8*)&sa_lo[rr * 40 + kgrp * 8];
        }
#pragma unroll
        for (int ni = 0; ni < 4; ni++) {
            int c = wc * 64 + ni * 16 + lrow;
            bh[ni]  = *(const bf16x8*)&sb_hi[c * 40 + kgrp * 8];
            blo[ni] = *(const bf16x8*)&sb_lo[c * 40 + kgrp * 8];
        }
#pragma unroll
        for (int mi = 0; mi < 4; mi++)
#pragma unroll
            for (int ni = 0; ni < 4; ni++) {
                acc[mi][ni] = __builtin_amdgcn_mfma_f32_16x16x32_bf16(ah[mi], bh[ni],  acc[mi][ni], 0, 0, 0);
                acc[mi][ni] = __builtin_amdgcn_mfma_f32_16x16x32_bf16(ah[mi], blo[ni], acc[mi][ni], 0, 0, 0);
                acc[mi][ni] = __builtin_amdgcn_mfma_f32_16x16x32_bf16(al[mi], bh[ni],  acc[mi][ni], 0, 0, 0);
            }
    }
    // epilogue: C/D col = lane&15, row = (lane>>4)*4 + reg; fused pw-dot
    float pwv[4];
#pragma unroll
    for (int ni = 0; ni < 4; ni++) pwv[ni] = pw[wc * 64 + ni * 16 + lrow];
#pragma unroll
    for (int mi = 0; mi < 4; mi++) {
        float dotq[4] = {0.f, 0.f, 0.f, 0.f};
#pragma unroll
        for (int ni = 0; ni < 4; ni++) {
            int c = wc * 64 + ni * 16 + lrow;
            float b = bl[c];
#pragma unroll
            for (int q = 0; q < 4; q++) {
                float v = fmaxf(acc[mi][ni][q] + b, 0.f);
                g_h2[(size_t)(row0 + wr * 64 + mi * 16 + kgrp * 4 + q) * 128 + c] = v;
                dotq[q] += v * pwv[ni];
            }
        }
#pragma unroll
        for (int q = 0; q < 4; q++) {
            float dv = dotq[q];
            dv += __shfl_xor(dv, 1); dv += __shfl_xor(dv, 2);
            dv += __shfl_xor(dv, 4); dv += __shfl_xor(dv, 8);
            if (lrow == 0)
                atomicAdd(&g_dot[row0 + wr * 64 + mi * 16 + kgrp * 4 + q], dv);
        }
    }
}

// ---- per-graph top-K on raw dots (tanh monotonic); selval = tanh(dot/||pw||) ----
__global__ void k_topk(int M, int K, int rr) {
    __shared__ float sc[1024];
    __shared__ int   id[1024];
    int g = blockIdx.x, tid = threadIdx.x;
    float invn = 1.f / g_pwnorm[rr];
    for (int i = tid; i < 1024; i += 512) {
        sc[i] = (i < M) ? g_dot[g * M + i] : -INFINITY;
        id[i] = i;
    }
    for (int i = tid; i < M; i += 512) g_newid[g * M + i] = -1;
    __syncthreads();
    for (int k = 2; k <= 1024; k <<= 1) {
        for (int j = k >> 1; j > 0; j >>= 1) {
            for (int i = tid; i < 1024; i += 512) {
                int ixj = i ^ j;
                if (ixj > i) {
                    bool desc = ((i & k) == 0);
                    float a = sc[i], b = sc[ixj];
                    bool sw = desc ? (a < b) : (a > b);
                    if (sw) {
                        sc[i] = b; sc[ixj] = a;
                        int t = id[i]; id[i] = id[ixj]; id[ixj] = t;
                    }
                }
            }
            __syncthreads();
        }
    }
    for (int j = tid; j < K; j += 512) {
        int li = id[j];
        g_selidx[g * K + j] = g * M + li;
        g_selval[g * K + j] = tanhf(sc[j] * invn);
        g_newid[g * M + li] = g * K + j;
    }
}

// ---- gather x_new = h2[sel]*val -> g_h (f32) + hi/lo planes; partial readout ----
__global__ void k_gather_pool(int K, int rr) {
    int g = blockIdx.x, chunk = blockIdx.y;   // linear b%8 = g%8 (XCD locality)
    int cs = (K + 7) / 8;
    int j0 = chunk * cs, j1 = min(K, j0 + cs);
    int tid = threadIdx.x;
    int c = tid & 127, half = tid >> 7;
    float mx = -INFINITY, sm = 0.f;
    for (int j = j0 + half; j < j1; j += 2) {
        int srcRow = g_selidx[g * K + j];
        float v = g_h2[(size_t)srcRow * 128 + c] * g_selval[g * K + j];
        size_t o = (size_t)(g * K + j) * 128 + c;
        g_h[o] = v;
        split2(v, g_xh[o], g_xl[o]);
        mx = fmaxf(mx, v); sm += v;
    }
    __shared__ float smx[256], ssm[256];
    smx[tid] = mx; ssm[tid] = sm;
    __syncthreads();
    if (half == 0) {
        mx = fmaxf(mx, smx[tid + 128]);
        sm += ssm[tid + 128];
        g_pool[((rr * NGRAPH + g) * 8 + chunk) * 256 + c] = mx;
        g_pool[((rr * NGRAPH + g) * 8 + chunk) * 256 + 128 + c] = sm;
    }
}

// ---- final MLP head (fused 3-round readout combine) ----
__global__ void k_mlp(const float* __restrict__ W1, const float* __restrict__ b1,
                      const float* __restrict__ W2, const float* __restrict__ b2,
                      const float* __restrict__ W3, const float* __restrict__ b3,
                      float* __restrict__ out, int K0, int K1, int K2) {
    int g = blockIdx.x, tid = threadIdx.x;   // 128 threads
    __shared__ float s_sh[256], h1[128], h2v[64], red[128];
    float Kf[3] = {(float)K0, (float)K1, (float)K2};
    float accmax = 0.f, accmean = 0.f;
    for (int r = 0; r < 3; r++) {
        float mx = -INFINITY, sm = 0.f;
        for (int ch = 0; ch < 8; ch++) {
            const float* p = &g_pool[((r * NGRAPH + g) * 8 + ch) * 256];
            mx = fmaxf(mx, p[tid]);
            sm += p[128 + tid];
        }
        accmax += mx;
        accmean += sm / Kf[r];
    }
    s_sh[tid] = accmax; s_sh[128 + tid] = accmean;
    __syncthreads();
    float a = 0.f;
    for (int k = 0; k < 256; k++) a += s_sh[k] * W1[k * 128 + tid];
    h1[tid] = fmaxf(a + b1[tid], 0.f);
    __syncthreads();
    if (tid < 64) {
        float a2 = 0.f;
        for (int k = 0; k < 128; k++) a2 += h1[k] * W2[k * 64 + tid];
        h2v[tid] = fmaxf(a2 + b2[tid], 0.f);
    }
    __syncthreads();
    red[tid] = (tid < 64) ? h2v[tid] * W3[tid] : 0.f;
    __syncthreads();
    for (int s = 64; s > 0; s >>= 1) {
        if (tid < s) red[tid] += red[tid + s];
        __syncthreads();
    }
    if (tid == 0) {
        float z = red[0] + b3[0];
        out[g] = 1.f / (1.f + expf(-z));
    }
}

extern "C" void kernel_launch(void* const* d_in, const int* in_sizes, int n_in,
                              void* d_out, int out_size, void* d_ws, size_t ws_size,
                              hipStream_t stream) {
    const float* x  = (const float*)d_in[0];
    const int*   ei = (const int*)d_in[1];
    const float* Wl[3] = {(const float*)d_in[2], (const float*)d_in[6],  (const float*)d_in[10]};
    const float* bl[3] = {(const float*)d_in[3], (const float*)d_in[7],  (const float*)d_in[11]};
    const float* Wr[3] = {(const float*)d_in[4], (const float*)d_in[8],  (const float*)d_in[12]};
    const float* pw[3] = {(const float*)d_in[5], (const float*)d_in[9],  (const float*)d_in[13]};
    const float* W1 = (const float*)d_in[14]; const float* b1 = (const float*)d_in[15];
    const float* W2 = (const float*)d_in[16]; const float* b2 = (const float*)d_in[17];
    const float* W3 = (const float*)d_in[18]; const float* b3 = (const float*)d_in[19];
    float* out = (float*)d_out;

    const int Ms[3] = {1024, 820, 656};
    const int Ks[3] = {820, 656, 525};

    k_prep_w<<<384, 256, 0, stream>>>(Wl[0], Wr[0], Wl[1], Wr[1], Wl[2], Wr[2]);
    k_norms<<<3, 64, 0, stream>>>(pw[0], pw[1], pw[2]);
    k_prep_x<<<NTOT * D / 4 / 256, 256, 0, stream>>>(x);

    for (int r = 0; r < 3; r++) {
        int M = Ms[r], K = Ks[r];
        int n = NGRAPH * M;                  // 65536 / 52480 / 41984 (all %128==0)
        int BPG = (M + 7) / 8;
        int ab = (r == 1) ? 1 : 0;           // adjacency buffer for this round
        if (r == 0)
            k_badj0<<<NGRAPH, 1024, 0, stream>>>(ei);
        else
            k_compact<<<(n + 3) / 4, 256, 0, stream>>>(n, r - 1); // r=1: A->B, r=2: B->A
        k_aggregate<<<NGRAPH * BPG, 256, 0, stream>>>(x, (r == 0) ? 1 : 0, ab, M, BPG);
        k_gemm<<<n / 128, 256, 0, stream>>>(r, bl[r], pw[r]);
        k_topk<<<NGRAPH, 512, 0, stream>>>(M, K, r);
        k_gather_pool<<<dim3(NGRAPH, 8), 256, 0, stream>>>(K, r);
    }
    k_mlp<<<NGRAPH, 128, 0, stream>>>(W1, b1, W2, b2, W3, b3, out,
                                      Ks[0], Ks[1], Ks[2]);
}